// Round 4
// baseline (1136.780 us; speedup 1.0000x reference)
//
#include <hip/hip_runtime.h>
#include <hip/hip_bf16.h>
#include <stdint.h>

// B=8, S=1024, D=512, H=8, DK=512 (H*DK=4096).
// CONTRACT (decoded r0-5): inputs fp32, OUTPUT fp32, ws = 256 MiB exactly.
// R12 == R11 resubmit (container infra failure, no kernel verdict).
// flash_attn keeps R10's lockstep (K-DMA + V issued at top, vmcnt(8) B1,
// full-drain B2) but V goes global->VGPR instead of LDS: removes the 4-way
// conflicted Vs reads (~45% of LDS traffic) and 32KB LDS. B0 dropped (safe:
// B2 barrier orders Ks overwrite + Ps reuse). l-reduction deferred to epilogue.
// GEMMs: inputs pre-converted to bf16 (cvt6 before qkv into dead ctx region;
// cvt1 wfc after attn into dead Qh region) -> both operands staged via
// global_load_lds width=16, zero staging VALU, halved operand bytes.
typedef __attribute__((ext_vector_type(8))) short short8;
typedef __attribute__((ext_vector_type(4))) float f32x4;

__device__ __forceinline__ short f2bf(float f) {
  __hip_bfloat16 h = __float2bfloat16(f);  // v_cvt-class RNE
  union { __hip_bfloat16 h; short s; } x;
  x.h = h;
  return x.s;
}
// async global->LDS, 16B/lane; lds ptr must equal wave-uniform base + lane*16
__device__ __forceinline__ void g2lds16(const void* g, void* l) {
  __builtin_amdgcn_global_load_lds(
      (const __attribute__((address_space(1))) void*)g,
      (__attribute__((address_space(3))) void*)l, 16, 0, 0);
}

// ---------------------------------------------------------------------------
// K0a: fp32 -> bf16 pre-convert for qkv inputs+weights (one launch, z picks).
// z<3: q/k/v (4.19M elems each) -> xb+z*4194304. z>=3: wq/wk/wv (2.10M) -> wb.
// ---------------------------------------------------------------------------
__global__ void cvt6(const float* __restrict__ q, const float* __restrict__ k,
                     const float* __restrict__ v, const float* __restrict__ wq,
                     const float* __restrict__ wk, const float* __restrict__ wv,
                     short* __restrict__ xb, short* __restrict__ wb)
{
  const int z = blockIdx.z;
  const float* s;
  short* d;
  long nvec;
  if (z < 3) { s = (z == 0) ? q : (z == 1) ? k : v;  d = xb + (long)z * 4194304; nvec = 524288; }
  else       { s = (z == 3) ? wq : (z == 4) ? wk : wv; d = wb + (long)(z - 3) * 2097152; nvec = 262144; }
  const long stride = (long)gridDim.x * blockDim.x;
  for (long i = (long)blockIdx.x * blockDim.x + threadIdx.x; i < nvec; i += stride) {
    f32x4 a = *(const f32x4*)(s + i * 8);
    f32x4 b = *(const f32x4*)(s + i * 8 + 4);
    short8 o;
#pragma unroll
    for (int t = 0; t < 4; ++t) { o[t] = f2bf(a[t]); o[4 + t] = f2bf(b[t]); }
    *(short8*)(d + i * 8) = o;
  }
}

// K0b: single-array fp32->bf16 (for wfc, launched after attn).
__global__ void cvt1(const float* __restrict__ s, short* __restrict__ d, int nvec)
{
  const long stride = (long)gridDim.x * blockDim.x;
  for (long i = (long)blockIdx.x * blockDim.x + threadIdx.x; i < nvec; i += stride) {
    f32x4 a = *(const f32x4*)(s + i * 8);
    f32x4 b = *(const f32x4*)(s + i * 8 + 4);
    short8 o;
#pragma unroll
    for (int t = 0; t < 4; ++t) { o[t] = f2bf(a[t]); o[4 + t] = f2bf(b[t]); }
    *(short8*)(d + i * 8) = o;
  }
}

// ---------------------------------------------------------------------------
// K1: QKV projection, all-bf16 inputs, both operands DMA-staged.
// M=8192, N=4096, K=512. z=0/1 -> (B,H,S,DK); z=2 (V) -> (B,H,DK,S).
// LDS layout is linear in c (byte off = c*16), matching global_load_lds.
// ---------------------------------------------------------------------------
__global__ void qkv_proj(
    const short* __restrict__ xb, const short* __restrict__ wb,
    short* __restrict__ Qh, short* __restrict__ Kh, short* __restrict__ Vt)
{
  __shared__ __align__(16) short As[128 * 32];
  __shared__ __align__(16) short Bs[128 * 32];
  const int z = blockIdx.z;
  const short* x = xb + (long)z * 4194304;
  const short* W = wb + (long)z * 2097152;
  short* out = (z == 0) ? Qh : (z == 1) ? Kh : Vt;
  const int tid = threadIdx.x;
  const int wave = tid >> 6, lane = tid & 63;
  const int quad = lane >> 4, l15 = lane & 15;
  const int mBase = blockIdx.x * 128, nBase = blockIdx.y * 128;
  const int wm = wave >> 1, wn = wave & 1;
  const int c0 = tid, c1 = tid + 256;
  const int r0 = c0 >> 2, o0 = (c0 & 3) * 8;
  const int r1 = c1 >> 2, o1 = (c1 & 3) * 8;
  f32x4 acc[4][4] = {};

  for (int k0 = 0; k0 < 512; k0 += 32) {
    __syncthreads();
    g2lds16(x + (long)(mBase + r0) * 512 + k0 + o0, (char*)As + c0 * 16);
    g2lds16(x + (long)(mBase + r1) * 512 + k0 + o1, (char*)As + c1 * 16);
    g2lds16(W + (long)(nBase + r0) * 512 + k0 + o0, (char*)Bs + c0 * 16);
    g2lds16(W + (long)(nBase + r1) * 512 + k0 + o1, (char*)Bs + c1 * 16);
    __syncthreads();  // drains vmcnt: tiles visible
    short8 a[4], b[4];
#pragma unroll
    for (int mi = 0; mi < 4; ++mi)
      a[mi] = *(const short8*)(As + (wm * 64 + mi * 16 + l15) * 32 + quad * 8);
#pragma unroll
    for (int ni = 0; ni < 4; ++ni)
      b[ni] = *(const short8*)(Bs + (wn * 64 + ni * 16 + l15) * 32 + quad * 8);
#pragma unroll
    for (int mi = 0; mi < 4; ++mi)
#pragma unroll
      for (int ni = 0; ni < 4; ++ni)
        acc[mi][ni] = __builtin_amdgcn_mfma_f32_16x16x32_bf16(a[mi], b[ni], acc[mi][ni], 0, 0, 0);
  }
#pragma unroll
  for (int mi = 0; mi < 4; ++mi) {
#pragma unroll
    for (int ni = 0; ni < 4; ++ni) {
      int n = nBase + wn * 64 + ni * 16 + l15;
      int h = n >> 9, d = n & 511;
#pragma unroll
      for (int r = 0; r < 4; ++r) {
        int m = mBase + wm * 64 + mi * 16 + quad * 4 + r;
        int b = m >> 10, s = m & 1023;
        long idx;
        if (z == 2) idx = ((long)(b * 8 + h) * 512 + d) * 1024 + s;   // V: (B,H,DK,S)
        else        idx = ((long)(b * 8 + h) * 1024 + s) * 512 + d;   // (B,H,S,DK)
        out[idx] = f2bf(acc[mi][ni][r]);
      }
    }
  }
}

// ---------------------------------------------------------------------------
// K2: flash attention (lockstep, V in registers).
//  - Ks XOR-swizzled (chunk j of key-row r at r*64+(j^(r&7))), single buffer.
//  - V fragments: 8x short8 global->VGPR per wave (own 128-d slice), issued
//    at iteration top AFTER the K DMAs -> vmcnt(8) at B1 waits K only; V's
//    latency hides under QK^T+softmax; B2 (__syncthreads) drains it -> the
//    per-iter drain that keeps the 16 qt-blocks/bh L2-aligned is preserved.
//  - 2 barriers/iter (B0 dropped: B2's barrier already orders Ks overwrite
//    and Ps reuse across waves).
//  - l-reduction deferred out of the loop (lane-local partial sums).
//  - Ps rows padded to 40 shorts. PV d-split across waves.
//  - XCD swizzle: lin = (bh&7) + 8*(qt + 16*(bh>>3)).
// ---------------------------------------------------------------------------
__global__ __launch_bounds__(256, 2) void flash_attn(
    const short* __restrict__ Qh, const short* __restrict__ Kh,
    const short* __restrict__ Vt, short* __restrict__ ctx)
{
  __shared__ __align__(16) short Ks[32 * 512];    // 32 KB, swizzled
  __shared__ __align__(16) short Ps[4 * 16 * 40]; // 5 KB, padded rows
  __shared__ float lred[64];
  const int tid = threadIdx.x;
  const int wave = tid >> 6, lane = tid & 63;
  const int quad = lane >> 4, l15 = lane & 15;
  const int lin = blockIdx.x;
  const int qt = (lin >> 3) & 15;
  const int bh = ((lin >> 7) << 3) | (lin & 7);
  const float C = 0.0637587234f;  // log2(e)/sqrt(512)

  // Q fragments for this wave's q-group (A-operand: A[m=l15][k=quad*8+j])
  const short* qbase = Qh + ((long)bh * 1024 + qt * 64 + wave * 16 + l15) * 512 + quad * 8;
  short8 qf[16];
#pragma unroll
  for (int c = 0; c < 16; ++c) qf[c] = *(const short8*)(qbase + c * 32);

  const short* kbase = Kh + (long)bh * 524288;
  // V B-frag base: row d = wave*128 + t*16 + l15, k-chunk quad*8 (+kt*32)
  const short* vbase = Vt + ((long)bh * 512 + wave * 128 + l15) * 1024 + quad * 8;

  f32x4 acc[4][8] = {};               // O: [q-group][d-tile of this wave's slice]
  float l[4] = {0.f, 0.f, 0.f, 0.f};  // lane-local partial denominators

  for (int kt = 0; kt < 32; ++kt) {
#pragma unroll
    for (int i = 0; i < 8; ++i) {     // K tile: source chunk permuted per row
      int c = i * 256 + tid;
      int r = c >> 6, j = (c & 63) ^ (r & 7);
      g2lds16(kbase + (long)(kt * 32 + r) * 512 + j * 8, (char*)Ks + c * 16);
    }
    __builtin_amdgcn_sched_barrier(0);  // K DMAs issued before V loads
    short8 vf[8];
#pragma unroll
    for (int t = 0; t < 8; ++t)
      vf[t] = *(const short8*)(vbase + t * 16384 + kt * 32);
    __builtin_amdgcn_sched_barrier(0);
    // B1: wait K's 8 DMAs (oldest); V's 8 reg-loads remain in flight
    asm volatile("s_waitcnt vmcnt(8)" ::: "memory");
    __builtin_amdgcn_s_barrier();
    __builtin_amdgcn_sched_barrier(0);

    // S = Q K^T : own q-group x 32 keys
    f32x4 sacc[2] = {};
    __builtin_amdgcn_s_setprio(1);
#pragma unroll
    for (int nt = 0; nt < 2; ++nt)
#pragma unroll
      for (int c = 0; c < 16; ++c) {
        int row = nt * 16 + l15;
        int j = (c * 4 + quad) ^ (row & 7);
        short8 kf = *(const short8*)(Ks + row * 512 + j * 8);
        sacc[nt] = __builtin_amdgcn_mfma_f32_16x16x32_bf16(qf[c], kf, sacc[nt], 0, 0, 0);
      }
    __builtin_amdgcn_s_setprio(0);
    // p = exp2(s*C); lane-local partial sums; P into padded LDS
#pragma unroll
    for (int r = 0; r < 4; ++r) {
      float p0 = exp2f(sacc[0][r] * C);
      float p1 = exp2f(sacc[1][r] * C);
      Ps[wave * 640 + (quad * 4 + r) * 40 + l15]      = f2bf(p0);
      Ps[wave * 640 + (quad * 4 + r) * 40 + 16 + l15] = f2bf(p1);
      l[r] += p0 + p1;
    }
    __syncthreads();  // B2: full drain (V regs landed; Ps visible; lockstep)

    // O += P V : all 4 q-groups x this wave's 128-d slice (V from regs)
    __builtin_amdgcn_s_setprio(1);
#pragma unroll
    for (int g = 0; g < 4; ++g) {
      short8 pf = *(const short8*)(Ps + g * 640 + l15 * 40 + quad * 8);
#pragma unroll
      for (int t = 0; t < 8; ++t)
        acc[g][t] = __builtin_amdgcn_mfma_f32_16x16x32_bf16(pf, vf[t], acc[g][t], 0, 0, 0);
    }
    __builtin_amdgcn_s_setprio(0);
  }
  // deferred denominator reduction (within each quad's 16 lanes)
#pragma unroll
  for (int r = 0; r < 4; ++r) {
    float t = l[r];
    t += __shfl_xor(t, 1);
    t += __shfl_xor(t, 2);
    t += __shfl_xor(t, 4);
    t += __shfl_xor(t, 8);
    l[r] = t;
  }
  if (l15 == 0) {
#pragma unroll
    for (int r = 0; r < 4; ++r) lred[wave * 16 + quad * 4 + r] = l[r];
  }
  __syncthreads();
  // epilogue: /l, store ctx (B,S,H*DK), this wave's d-slice
  const int b = bh >> 3, h = bh & 7;
#pragma unroll
  for (int g = 0; g < 4; ++g) {
#pragma unroll
    for (int r = 0; r < 4; ++r) {
      float inv = 1.0f / lred[g * 16 + quad * 4 + r];
      int qrow = qt * 64 + g * 16 + quad * 4 + r;
      long base = ((long)(b * 1024 + qrow)) * 4096 + h * 512 + wave * 128;
#pragma unroll
      for (int t = 0; t < 8; ++t)
        ctx[base + t * 16 + l15] = f2bf(acc[g][t][r] * inv);
    }
  }
}

// ---------------------------------------------------------------------------
// K3: fc + residual, both operands DMA-staged (W pre-converted to bf16).
// M=8192, N=512, K=4096.
// ---------------------------------------------------------------------------
__global__ void fc_gemm(
    const short* __restrict__ A, const short* __restrict__ Wb,
    const float* __restrict__ resid, float* __restrict__ Y)
{
  __shared__ __align__(16) short As[128 * 32];
  __shared__ __align__(16) short Bs[128 * 32];
  const int tid = threadIdx.x;
  const int wave = tid >> 6, lane = tid & 63;
  const int quad = lane >> 4, l15 = lane & 15;
  const int mBase = blockIdx.x * 128, nBase = blockIdx.y * 128;
  const int wm = wave >> 1, wn = wave & 1;
  const int c0 = tid, c1 = tid + 256;
  const int r0 = c0 >> 2, o0 = (c0 & 3) * 8;
  const int r1 = c1 >> 2, o1 = (c1 & 3) * 8;
  f32x4 acc[4][4] = {};

  for (int k0 = 0; k0 < 4096; k0 += 32) {
    __syncthreads();
    g2lds16(A + (long)(mBase + r0) * 4096 + k0 + o0, (char*)As + c0 * 16);
    g2lds16(A + (long)(mBase + r1) * 4096 + k0 + o1, (char*)As + c1 * 16);
    g2lds16(Wb + (long)(nBase + r0) * 4096 + k0 + o0, (char*)Bs + c0 * 16);
    g2lds16(Wb + (long)(nBase + r1) * 4096 + k0 + o1, (char*)Bs + c1 * 16);
    __syncthreads();  // drains vmcnt: tiles visible
    short8 a[4], b[4];
#pragma unroll
    for (int mi = 0; mi < 4; ++mi)
      a[mi] = *(const short8*)(As + (wm * 64 + mi * 16 + l15) * 32 + quad * 8);
#pragma unroll
    for (int ni = 0; ni < 4; ++ni)
      b[ni] = *(const short8*)(Bs + (wn * 64 + ni * 16 + l15) * 32 + quad * 8);
#pragma unroll
    for (int mi = 0; mi < 4; ++mi)
#pragma unroll
      for (int ni = 0; ni < 4; ++ni)
        acc[mi][ni] = __builtin_amdgcn_mfma_f32_16x16x32_bf16(a[mi], b[ni], acc[mi][ni], 0, 0, 0);
  }
#pragma unroll
  for (int mi = 0; mi < 4; ++mi)
#pragma unroll
    for (int ni = 0; ni < 4; ++ni) {
      int n = nBase + wn * 64 + ni * 16 + l15;
#pragma unroll
      for (int r = 0; r < 4; ++r) {
        int m = mBase + wm * 64 + mi * 16 + quad * 4 + r;
        long idx = (long)m * 512 + n;
        Y[idx] = acc[mi][ni][r] + resid[idx];
      }
    }
}

// ---------------------------------------------------------------------------
// K4: LayerNorm (unchanged).
// ---------------------------------------------------------------------------
__global__ void layernorm(
    const float* __restrict__ Y, const float* __restrict__ gamma,
    const float* __restrict__ beta, float* __restrict__ out)
{
  const int tid = threadIdx.x;
  const int wave = tid >> 6, lane = tid & 63;
  const long row = (long)blockIdx.x * 4 + wave;
  f32x4 xa = *(const f32x4*)(Y + row * 512 + lane * 8);
  f32x4 xb = *(const f32x4*)(Y + row * 512 + lane * 8 + 4);
  float x[8];
  float s = 0.f, s2 = 0.f;
#pragma unroll
  for (int i = 0; i < 4; ++i) { x[i] = xa[i]; x[i + 4] = xb[i]; }
#pragma unroll
  for (int i = 0; i < 8; ++i) { s += x[i]; s2 += x[i] * x[i]; }
#pragma unroll
  for (int m = 1; m < 64; m <<= 1) { s += __shfl_xor(s, m); s2 += __shfl_xor(s2, m); }
  float mu = s * (1.0f / 512.0f);
  float var = s2 * (1.0f / 512.0f) - mu * mu;
  float rs = rsqrtf(var + 1e-6f);
  f32x4 oa, ob;
#pragma unroll
  for (int i = 0; i < 4; ++i) {
    oa[i] = (x[i] - mu) * rs * gamma[lane * 8 + i] + beta[lane * 8 + i];
    ob[i] = (x[i + 4] - mu) * rs * gamma[lane * 8 + 4 + i] + beta[lane * 8 + 4 + i];
  }
  *(f32x4*)(out + row * 512 + lane * 8) = oa;
  *(f32x4*)(out + row * 512 + lane * 8 + 4) = ob;
}

extern "C" void kernel_launch(void* const* d_in, const int* in_sizes, int n_in,
                              void* d_out, int out_size, void* d_ws, size_t ws_size,
                              hipStream_t stream) {
  const float* q     = (const float*)d_in[0];
  const float* k     = (const float*)d_in[1];
  const float* v     = (const float*)d_in[2];
  const float* wq    = (const float*)d_in[3];
  const float* wk    = (const float*)d_in[4];
  const float* wv    = (const float*)d_in[5];
  const float* wfc   = (const float*)d_in[6];
  const float* gamma = (const float*)d_in[7];
  const float* beta  = (const float*)d_in[8];
  float* out = (float*)d_out;
  char* ws = (char*)d_ws;
  short* Qh  = (short*)(ws);                    // [0,64M)   bf16, dead after attn
  short* Kh  = (short*)(ws + 67108864);         // [64,128M)
  short* Vt  = (short*)(ws + 134217728);        // [128,192M)
  short* ctx = (short*)(ws + 201326592);        // [192,256M) attn out (bf16)
  // cvt6 outputs live in the ctx region BEFORE attn overwrites it:
  short* xb  = (short*)(ws + 201326592);        // q/k/v bf16: 3 x 8 MB
  short* wb  = xb + 3 * 4194304;                // wq/wk/wv bf16: 3 x 4 MB
  // wfc bf16 lives in the dead-Qh region AFTER attn (Y uses [0,16M) fp32):
  short* wfcb = (short*)(ws + 16777216);        // [16,20M)
  float* Y   = (float*)(ws);                    // fp32 [0,16M), aliases dead Qh

  cvt6<<<dim3(1024, 1, 6), 256, 0, stream>>>(q, k, v, wq, wk, wv, xb, wb);
  qkv_proj<<<dim3(64, 32, 3), 256, 0, stream>>>(xb, wb, Qh, Kh, Vt);
  flash_attn<<<dim3(1024), 256, 0, stream>>>(Qh, Kh, Vt, ctx);
  cvt1<<<dim3(1024), 256, 0, stream>>>(wfc, wfcb, 262144);
  fc_gemm<<<dim3(64, 4), 256, 0, stream>>>(ctx, wfcb, q, Y);
  layernorm<<<2048, 256, 0, stream>>>(Y, gamma, beta, out);
}

// Round 5
// 725.324 us; speedup vs baseline: 1.5673x; 1.5673x over previous
//
#include <hip/hip_runtime.h>
#include <hip/hip_bf16.h>
#include <stdint.h>

// B=8, S=1024, D=512, H=8, DK=512 (H*DK=4096).
// CONTRACT (decoded r0-5): inputs fp32, OUTPUT fp32, ws = 256 MiB exactly.
// R13: recomposition of measured-best parts.
//  - flash_attn: R10's exact lockstep V-in-LDS structure (420us, FETCH 200MB).
//    n=2 evidence (R9, R12): per-lane V->VGPR loads collapse cross-block L2
//    reuse (FETCH 1.6-2.1GB) regardless of barrier placement; V MUST go via
//    global_load_lds DMA. Only delta vs R10: l-reduction deferred (reg-only).
//  - GEMMs: R12's validated pipeline (361us): bf16 pre-convert (cvt6/cvt1),
//    both operands staged via global_load_lds width=16.
typedef __attribute__((ext_vector_type(8))) short short8;
typedef __attribute__((ext_vector_type(4))) float f32x4;

__device__ __forceinline__ short f2bf(float f) {
  __hip_bfloat16 h = __float2bfloat16(f);  // v_cvt-class RNE
  union { __hip_bfloat16 h; short s; } x;
  x.h = h;
  return x.s;
}
// async global->LDS, 16B/lane; lds ptr must equal wave-uniform base + lane*16
__device__ __forceinline__ void g2lds16(const void* g, void* l) {
  __builtin_amdgcn_global_load_lds(
      (const __attribute__((address_space(1))) void*)g,
      (__attribute__((address_space(3))) void*)l, 16, 0, 0);
}

// ---------------------------------------------------------------------------
// K0a: fp32 -> bf16 pre-convert for qkv inputs+weights (one launch, z picks).
// z<3: q/k/v (4.19M elems each) -> xb+z*4194304. z>=3: wq/wk/wv (2.10M) -> wb.
// ---------------------------------------------------------------------------
__global__ void cvt6(const float* __restrict__ q, const float* __restrict__ k,
                     const float* __restrict__ v, const float* __restrict__ wq,
                     const float* __restrict__ wk, const float* __restrict__ wv,
                     short* __restrict__ xb, short* __restrict__ wb)
{
  const int z = blockIdx.z;
  const float* s;
  short* d;
  long nvec;
  if (z < 3) { s = (z == 0) ? q : (z == 1) ? k : v;  d = xb + (long)z * 4194304; nvec = 524288; }
  else       { s = (z == 3) ? wq : (z == 4) ? wk : wv; d = wb + (long)(z - 3) * 2097152; nvec = 262144; }
  const long stride = (long)gridDim.x * blockDim.x;
  for (long i = (long)blockIdx.x * blockDim.x + threadIdx.x; i < nvec; i += stride) {
    f32x4 a = *(const f32x4*)(s + i * 8);
    f32x4 b = *(const f32x4*)(s + i * 8 + 4);
    short8 o;
#pragma unroll
    for (int t = 0; t < 4; ++t) { o[t] = f2bf(a[t]); o[4 + t] = f2bf(b[t]); }
    *(short8*)(d + i * 8) = o;
  }
}

// K0b: single-array fp32->bf16 (for wfc, launched after attn).
__global__ void cvt1(const float* __restrict__ s, short* __restrict__ d, int nvec)
{
  const long stride = (long)gridDim.x * blockDim.x;
  for (long i = (long)blockIdx.x * blockDim.x + threadIdx.x; i < nvec; i += stride) {
    f32x4 a = *(const f32x4*)(s + i * 8);
    f32x4 b = *(const f32x4*)(s + i * 8 + 4);
    short8 o;
#pragma unroll
    for (int t = 0; t < 4; ++t) { o[t] = f2bf(a[t]); o[4 + t] = f2bf(b[t]); }
    *(short8*)(d + i * 8) = o;
  }
}

// ---------------------------------------------------------------------------
// K1: QKV projection, all-bf16 inputs, both operands DMA-staged.
// M=8192, N=4096, K=512. z=0/1 -> (B,H,S,DK); z=2 (V) -> (B,H,DK,S).
// ---------------------------------------------------------------------------
__global__ void qkv_proj(
    const short* __restrict__ xb, const short* __restrict__ wb,
    short* __restrict__ Qh, short* __restrict__ Kh, short* __restrict__ Vt)
{
  __shared__ __align__(16) short As[128 * 32];
  __shared__ __align__(16) short Bs[128 * 32];
  const int z = blockIdx.z;
  const short* x = xb + (long)z * 4194304;
  const short* W = wb + (long)z * 2097152;
  short* out = (z == 0) ? Qh : (z == 1) ? Kh : Vt;
  const int tid = threadIdx.x;
  const int wave = tid >> 6, lane = tid & 63;
  const int quad = lane >> 4, l15 = lane & 15;
  const int mBase = blockIdx.x * 128, nBase = blockIdx.y * 128;
  const int wm = wave >> 1, wn = wave & 1;
  const int c0 = tid, c1 = tid + 256;
  const int r0 = c0 >> 2, o0 = (c0 & 3) * 8;
  const int r1 = c1 >> 2, o1 = (c1 & 3) * 8;
  f32x4 acc[4][4] = {};

  for (int k0 = 0; k0 < 512; k0 += 32) {
    __syncthreads();
    g2lds16(x + (long)(mBase + r0) * 512 + k0 + o0, (char*)As + c0 * 16);
    g2lds16(x + (long)(mBase + r1) * 512 + k0 + o1, (char*)As + c1 * 16);
    g2lds16(W + (long)(nBase + r0) * 512 + k0 + o0, (char*)Bs + c0 * 16);
    g2lds16(W + (long)(nBase + r1) * 512 + k0 + o1, (char*)Bs + c1 * 16);
    __syncthreads();  // drains vmcnt: tiles visible
    short8 a[4], b[4];
#pragma unroll
    for (int mi = 0; mi < 4; ++mi)
      a[mi] = *(const short8*)(As + (wm * 64 + mi * 16 + l15) * 32 + quad * 8);
#pragma unroll
    for (int ni = 0; ni < 4; ++ni)
      b[ni] = *(const short8*)(Bs + (wn * 64 + ni * 16 + l15) * 32 + quad * 8);
#pragma unroll
    for (int mi = 0; mi < 4; ++mi)
#pragma unroll
      for (int ni = 0; ni < 4; ++ni)
        acc[mi][ni] = __builtin_amdgcn_mfma_f32_16x16x32_bf16(a[mi], b[ni], acc[mi][ni], 0, 0, 0);
  }
#pragma unroll
  for (int mi = 0; mi < 4; ++mi) {
#pragma unroll
    for (int ni = 0; ni < 4; ++ni) {
      int n = nBase + wn * 64 + ni * 16 + l15;
      int h = n >> 9, d = n & 511;
#pragma unroll
      for (int r = 0; r < 4; ++r) {
        int m = mBase + wm * 64 + mi * 16 + quad * 4 + r;
        int b = m >> 10, s = m & 1023;
        long idx;
        if (z == 2) idx = ((long)(b * 8 + h) * 512 + d) * 1024 + s;   // V: (B,H,DK,S)
        else        idx = ((long)(b * 8 + h) * 1024 + s) * 512 + d;   // (B,H,S,DK)
        out[idx] = f2bf(acc[mi][ni][r]);
      }
    }
  }
}

// ---------------------------------------------------------------------------
// K2: flash attention (R10 lockstep structure, V in LDS).
//  - Ks XOR-swizzled: chunk j of key-row r lives at r*64 + (j ^ (r&7)).
//  - Vs XOR-swizzled: chunk j of d-row lives at d*4 + (j ^ (d&3)).
//  - Ps rows padded to 40 shorts.
//  - B0: syncthreads (prior reads done before overwrite).
//  - B1: vmcnt(8) waits K only; V's 8 DMAs hide under QK^T+softmax.
//  - B2: syncthreads full drain -> lockstep, cross-block L2 sharing intact.
//  - l-reduction deferred out of the loop (register-only change vs R10).
//  - PV d-split across waves; denominators broadcast via lred[64].
//  - XCD swizzle: lin = (bh&7) + 8*(qt + 16*(bh>>3)).
// ---------------------------------------------------------------------------
__global__ __launch_bounds__(256, 2) void flash_attn(
    const short* __restrict__ Qh, const short* __restrict__ Kh,
    const short* __restrict__ Vt, short* __restrict__ ctx)
{
  __shared__ __align__(16) short Ks[32 * 512];    // 32 KB, swizzled
  __shared__ __align__(16) short Vs[512 * 32];    // 32 KB, swizzled
  __shared__ __align__(16) short Ps[4 * 16 * 40]; // 5 KB, padded rows
  __shared__ float lred[64];
  const int tid = threadIdx.x;
  const int wave = tid >> 6, lane = tid & 63;
  const int quad = lane >> 4, l15 = lane & 15;
  const int lin = blockIdx.x;
  const int qt = (lin >> 3) & 15;
  const int bh = ((lin >> 7) << 3) | (lin & 7);
  const float C = 0.0637587234f;  // log2(e)/sqrt(512)

  // Q fragments for this wave's q-group (A-operand: A[m=l15][k=quad*8+j])
  const short* qbase = Qh + ((long)bh * 1024 + qt * 64 + wave * 16 + l15) * 512 + quad * 8;
  short8 qf[16];
#pragma unroll
  for (int c = 0; c < 16; ++c) qf[c] = *(const short8*)(qbase + c * 32);

  f32x4 acc[4][8] = {};               // O: [q-group][d-tile of this wave's slice]
  float l[4] = {0.f, 0.f, 0.f, 0.f};  // lane-local partial denominators

  for (int kt = 0; kt < 32; ++kt) {
    __syncthreads();  // B0: prior iter's Ks/Vs/Ps reads complete before overwrite
#pragma unroll
    for (int i = 0; i < 8; ++i) {     // K tile: source chunk permuted per row
      int c = i * 256 + tid;
      int r = c >> 6, j = (c & 63) ^ (r & 7);
      g2lds16(Kh + ((long)bh * 1024 + kt * 32 + r) * 512 + j * 8, (char*)Ks + c * 16);
    }
    __builtin_amdgcn_sched_barrier(0);  // pin issue order: K DMAs before V DMAs
#pragma unroll
    for (int i = 0; i < 8; ++i) {     // V tile: source chunk permuted per row
      int c = i * 256 + tid;
      int d = c >> 2, j = (c & 3) ^ (d & 3);
      g2lds16(Vt + ((long)bh * 512 + d) * 1024 + kt * 32 + j * 8, (char*)Vs + c * 16);
    }
    __builtin_amdgcn_sched_barrier(0);
    // B1: wait K's 8 DMAs only (V's 8 remain in flight, hidden under QK^T)
    asm volatile("s_waitcnt vmcnt(8)" ::: "memory");
    __builtin_amdgcn_s_barrier();
    __builtin_amdgcn_sched_barrier(0);

    // S = Q K^T : own q-group x 32 keys
    f32x4 sacc[2] = {};
#pragma unroll
    for (int nt = 0; nt < 2; ++nt)
#pragma unroll
      for (int c = 0; c < 16; ++c) {
        int row = nt * 16 + l15;
        int j = (c * 4 + quad) ^ (row & 7);
        short8 kf = *(const short8*)(Ks + row * 512 + j * 8);
        sacc[nt] = __builtin_amdgcn_mfma_f32_16x16x32_bf16(qf[c], kf, sacc[nt], 0, 0, 0);
      }
    // p = exp2(s*C); lane-local partial sums; P into padded LDS
#pragma unroll
    for (int r = 0; r < 4; ++r) {
      float p0 = exp2f(sacc[0][r] * C);
      float p1 = exp2f(sacc[1][r] * C);
      Ps[wave * 640 + (quad * 4 + r) * 40 + l15]      = f2bf(p0);
      Ps[wave * 640 + (quad * 4 + r) * 40 + 16 + l15] = f2bf(p1);
      l[r] += p0 + p1;
    }
    __syncthreads();  // B2: full drain (vmcnt->0: Vs landed; lgkm: Ps visible)

    // O += P V : all 4 q-groups x this wave's 128-d slice
#pragma unroll
    for (int g = 0; g < 4; ++g) {
      short8 pf = *(const short8*)(Ps + g * 640 + l15 * 40 + quad * 8);
#pragma unroll
      for (int t = 0; t < 8; ++t) {
        int row = wave * 128 + t * 16 + l15;
        int j = quad ^ (row & 3);
        short8 vf = *(const short8*)(Vs + row * 32 + j * 8);
        acc[g][t] = __builtin_amdgcn_mfma_f32_16x16x32_bf16(pf, vf, acc[g][t], 0, 0, 0);
      }
    }
  }
  // deferred denominator reduction (within each quad's 16 lanes)
#pragma unroll
  for (int r = 0; r < 4; ++r) {
    float t = l[r];
    t += __shfl_xor(t, 1);
    t += __shfl_xor(t, 2);
    t += __shfl_xor(t, 4);
    t += __shfl_xor(t, 8);
    l[r] = t;
  }
  if (l15 == 0) {
#pragma unroll
    for (int r = 0; r < 4; ++r) lred[wave * 16 + quad * 4 + r] = l[r];
  }
  __syncthreads();
  // epilogue: /l, store ctx (B,S,H*DK), this wave's d-slice
  const int b = bh >> 3, h = bh & 7;
#pragma unroll
  for (int g = 0; g < 4; ++g) {
#pragma unroll
    for (int r = 0; r < 4; ++r) {
      float inv = 1.0f / lred[g * 16 + quad * 4 + r];
      int qrow = qt * 64 + g * 16 + quad * 4 + r;
      long base = ((long)(b * 1024 + qrow)) * 4096 + h * 512 + wave * 128;
#pragma unroll
      for (int t = 0; t < 8; ++t)
        ctx[base + t * 16 + l15] = f2bf(acc[g][t][r] * inv);
    }
  }
}

// ---------------------------------------------------------------------------
// K3: fc + residual, both operands DMA-staged (W pre-converted to bf16).
// M=8192, N=512, K=4096.
// ---------------------------------------------------------------------------
__global__ void fc_gemm(
    const short* __restrict__ A, const short* __restrict__ Wb,
    const float* __restrict__ resid, float* __restrict__ Y)
{
  __shared__ __align__(16) short As[128 * 32];
  __shared__ __align__(16) short Bs[128 * 32];
  const int tid = threadIdx.x;
  const int wave = tid >> 6, lane = tid & 63;
  const int quad = lane >> 4, l15 = lane & 15;
  const int mBase = blockIdx.x * 128, nBase = blockIdx.y * 128;
  const int wm = wave >> 1, wn = wave & 1;
  const int c0 = tid, c1 = tid + 256;
  const int r0 = c0 >> 2, o0 = (c0 & 3) * 8;
  const int r1 = c1 >> 2, o1 = (c1 & 3) * 8;
  f32x4 acc[4][4] = {};

  for (int k0 = 0; k0 < 4096; k0 += 32) {
    __syncthreads();
    g2lds16(A + (long)(mBase + r0) * 4096 + k0 + o0, (char*)As + c0 * 16);
    g2lds16(A + (long)(mBase + r1) * 4096 + k0 + o1, (char*)As + c1 * 16);
    g2lds16(Wb + (long)(nBase + r0) * 4096 + k0 + o0, (char*)Bs + c0 * 16);
    g2lds16(Wb + (long)(nBase + r1) * 4096 + k0 + o1, (char*)Bs + c1 * 16);
    __syncthreads();  // drains vmcnt: tiles visible
    short8 a[4], b[4];
#pragma unroll
    for (int mi = 0; mi < 4; ++mi)
      a[mi] = *(const short8*)(As + (wm * 64 + mi * 16 + l15) * 32 + quad * 8);
#pragma unroll
    for (int ni = 0; ni < 4; ++ni)
      b[ni] = *(const short8*)(Bs + (wn * 64 + ni * 16 + l15) * 32 + quad * 8);
#pragma unroll
    for (int mi = 0; mi < 4; ++mi)
#pragma unroll
      for (int ni = 0; ni < 4; ++ni)
        acc[mi][ni] = __builtin_amdgcn_mfma_f32_16x16x32_bf16(a[mi], b[ni], acc[mi][ni], 0, 0, 0);
  }
#pragma unroll
  for (int mi = 0; mi < 4; ++mi)
#pragma unroll
    for (int ni = 0; ni < 4; ++ni) {
      int n = nBase + wn * 64 + ni * 16 + l15;
#pragma unroll
      for (int r = 0; r < 4; ++r) {
        int m = mBase + wm * 64 + mi * 16 + quad * 4 + r;
        long idx = (long)m * 512 + n;
        Y[idx] = acc[mi][ni][r] + resid[idx];
      }
    }
}

// ---------------------------------------------------------------------------
// K4: LayerNorm (unchanged).
// ---------------------------------------------------------------------------
__global__ void layernorm(
    const float* __restrict__ Y, const float* __restrict__ gamma,
    const float* __restrict__ beta, float* __restrict__ out)
{
  const int tid = threadIdx.x;
  const int wave = tid >> 6, lane = tid & 63;
  const long row = (long)blockIdx.x * 4 + wave;
  f32x4 xa = *(const f32x4*)(Y + row * 512 + lane * 8);
  f32x4 xb = *(const f32x4*)(Y + row * 512 + lane * 8 + 4);
  float x[8];
  float s = 0.f, s2 = 0.f;
#pragma unroll
  for (int i = 0; i < 4; ++i) { x[i] = xa[i]; x[i + 4] = xb[i]; }
#pragma unroll
  for (int i = 0; i < 8; ++i) { s += x[i]; s2 += x[i] * x[i]; }
#pragma unroll
  for (int m = 1; m < 64; m <<= 1) { s += __shfl_xor(s, m); s2 += __shfl_xor(s2, m); }
  float mu = s * (1.0f / 512.0f);
  float var = s2 * (1.0f / 512.0f) - mu * mu;
  float rs = rsqrtf(var + 1e-6f);
  f32x4 oa, ob;
#pragma unroll
  for (int i = 0; i < 4; ++i) {
    oa[i] = (x[i] - mu) * rs * gamma[lane * 8 + i] + beta[lane * 8 + i];
    ob[i] = (x[i + 4] - mu) * rs * gamma[lane * 8 + 4 + i] + beta[lane * 8 + 4 + i];
  }
  *(f32x4*)(out + row * 512 + lane * 8) = oa;
  *(f32x4*)(out + row * 512 + lane * 8 + 4) = ob;
}

extern "C" void kernel_launch(void* const* d_in, const int* in_sizes, int n_in,
                              void* d_out, int out_size, void* d_ws, size_t ws_size,
                              hipStream_t stream) {
  const float* q     = (const float*)d_in[0];
  const float* k     = (const float*)d_in[1];
  const float* v     = (const float*)d_in[2];
  const float* wq    = (const float*)d_in[3];
  const float* wk    = (const float*)d_in[4];
  const float* wv    = (const float*)d_in[5];
  const float* wfc   = (const float*)d_in[6];
  const float* gamma = (const float*)d_in[7];
  const float* beta  = (const float*)d_in[8];
  float* out = (float*)d_out;
  char* ws = (char*)d_ws;
  short* Qh  = (short*)(ws);                    // [0,64M)   bf16, dead after attn
  short* Kh  = (short*)(ws + 67108864);         // [64,128M)
  short* Vt  = (short*)(ws + 134217728);        // [128,192M)
  short* ctx = (short*)(ws + 201326592);        // [192,256M) attn out (bf16)
  // cvt6 outputs live in the ctx region BEFORE attn overwrites it:
  short* xb  = (short*)(ws + 201326592);        // q/k/v bf16: 3 x 8 MB
  short* wb  = xb + 3 * 4194304;                // wq/wk/wv bf16: 3 x 4 MB
  // wfc bf16 lives in the dead-Qh region AFTER attn (Y uses [0,16M) fp32):
  short* wfcb = (short*)(ws + 16777216);        // [16,20M)
  float* Y   = (float*)(ws);                    // fp32 [0,16M), aliases dead Qh

  cvt6<<<dim3(1024, 1, 6), 256, 0, stream>>>(q, k, v, wq, wk, wv, xb, wb);
  qkv_proj<<<dim3(64, 32, 3), 256, 0, stream>>>(xb, wb, Qh, Kh, Vt);
  flash_attn<<<dim3(1024), 256, 0, stream>>>(Qh, Kh, Vt, ctx);
  cvt1<<<dim3(1024), 256, 0, stream>>>(wfc, wfcb, 262144);
  fc_gemm<<<dim3(64, 4), 256, 0, stream>>>(ctx, wfcb, q, Y);
  layernorm<<<2048, 256, 0, stream>>>(Y, gamma, beta, out);
}

// Round 6
// 717.916 us; speedup vs baseline: 1.5834x; 1.0103x over previous
//
#include <hip/hip_runtime.h>
#include <hip/hip_bf16.h>
#include <stdint.h>

// B=8, S=1024, D=512, H=8, DK=512 (H*DK=4096).
// CONTRACT (decoded r0-5): inputs fp32, OUTPUT fp32, ws = 256 MiB exactly.
// R14 (from R13 best, 725us):
//  - flash_attn: hoist PV's V-fragment LDS reads out of the g-loop (vf[8] in
//    regs, read once per iter AFTER B2) -> PV LDS reads 128->32 KB/block-iter,
//    total LDS traffic -29%. Global/DMA path and barrier structure UNCHANGED
//    (lockstep preserved; FETCH guardrail ~180MB).
//  - fc_gemm: 128x64 tiles -> 512 blocks (2/CU, was 1/CU latency-exposed).
//  - everything else identical to R13.
typedef __attribute__((ext_vector_type(8))) short short8;
typedef __attribute__((ext_vector_type(4))) float f32x4;

__device__ __forceinline__ short f2bf(float f) {
  __hip_bfloat16 h = __float2bfloat16(f);  // v_cvt-class RNE
  union { __hip_bfloat16 h; short s; } x;
  x.h = h;
  return x.s;
}
// async global->LDS, 16B/lane; lds ptr must equal wave-uniform base + lane*16
__device__ __forceinline__ void g2lds16(const void* g, void* l) {
  __builtin_amdgcn_global_load_lds(
      (const __attribute__((address_space(1))) void*)g,
      (__attribute__((address_space(3))) void*)l, 16, 0, 0);
}

// ---------------------------------------------------------------------------
// K0a: fp32 -> bf16 pre-convert for qkv inputs+weights (one launch, z picks).
// ---------------------------------------------------------------------------
__global__ void cvt6(const float* __restrict__ q, const float* __restrict__ k,
                     const float* __restrict__ v, const float* __restrict__ wq,
                     const float* __restrict__ wk, const float* __restrict__ wv,
                     short* __restrict__ xb, short* __restrict__ wb)
{
  const int z = blockIdx.z;
  const float* s;
  short* d;
  long nvec;
  if (z < 3) { s = (z == 0) ? q : (z == 1) ? k : v;  d = xb + (long)z * 4194304; nvec = 524288; }
  else       { s = (z == 3) ? wq : (z == 4) ? wk : wv; d = wb + (long)(z - 3) * 2097152; nvec = 262144; }
  const long stride = (long)gridDim.x * blockDim.x;
  for (long i = (long)blockIdx.x * blockDim.x + threadIdx.x; i < nvec; i += stride) {
    f32x4 a = *(const f32x4*)(s + i * 8);
    f32x4 b = *(const f32x4*)(s + i * 8 + 4);
    short8 o;
#pragma unroll
    for (int t = 0; t < 4; ++t) { o[t] = f2bf(a[t]); o[4 + t] = f2bf(b[t]); }
    *(short8*)(d + i * 8) = o;
  }
}

// K0b: single-array fp32->bf16 (for wfc, launched after attn).
__global__ void cvt1(const float* __restrict__ s, short* __restrict__ d, int nvec)
{
  const long stride = (long)gridDim.x * blockDim.x;
  for (long i = (long)blockIdx.x * blockDim.x + threadIdx.x; i < nvec; i += stride) {
    f32x4 a = *(const f32x4*)(s + i * 8);
    f32x4 b = *(const f32x4*)(s + i * 8 + 4);
    short8 o;
#pragma unroll
    for (int t = 0; t < 4; ++t) { o[t] = f2bf(a[t]); o[4 + t] = f2bf(b[t]); }
    *(short8*)(d + i * 8) = o;
  }
}

// ---------------------------------------------------------------------------
// K1: QKV projection, all-bf16 inputs, both operands DMA-staged.
// M=8192, N=4096, K=512. z=0/1 -> (B,H,S,DK); z=2 (V) -> (B,H,DK,S).
// ---------------------------------------------------------------------------
__global__ void qkv_proj(
    const short* __restrict__ xb, const short* __restrict__ wb,
    short* __restrict__ Qh, short* __restrict__ Kh, short* __restrict__ Vt)
{
  __shared__ __align__(16) short As[128 * 32];
  __shared__ __align__(16) short Bs[128 * 32];
  const int z = blockIdx.z;
  const short* x = xb + (long)z * 4194304;
  const short* W = wb + (long)z * 2097152;
  short* out = (z == 0) ? Qh : (z == 1) ? Kh : Vt;
  const int tid = threadIdx.x;
  const int wave = tid >> 6, lane = tid & 63;
  const int quad = lane >> 4, l15 = lane & 15;
  const int mBase = blockIdx.x * 128, nBase = blockIdx.y * 128;
  const int wm = wave >> 1, wn = wave & 1;
  const int c0 = tid, c1 = tid + 256;
  const int r0 = c0 >> 2, o0 = (c0 & 3) * 8;
  const int r1 = c1 >> 2, o1 = (c1 & 3) * 8;
  f32x4 acc[4][4] = {};

  for (int k0 = 0; k0 < 512; k0 += 32) {
    __syncthreads();
    g2lds16(x + (long)(mBase + r0) * 512 + k0 + o0, (char*)As + c0 * 16);
    g2lds16(x + (long)(mBase + r1) * 512 + k0 + o1, (char*)As + c1 * 16);
    g2lds16(W + (long)(nBase + r0) * 512 + k0 + o0, (char*)Bs + c0 * 16);
    g2lds16(W + (long)(nBase + r1) * 512 + k0 + o1, (char*)Bs + c1 * 16);
    __syncthreads();  // drains vmcnt: tiles visible
    short8 a[4], b[4];
#pragma unroll
    for (int mi = 0; mi < 4; ++mi)
      a[mi] = *(const short8*)(As + (wm * 64 + mi * 16 + l15) * 32 + quad * 8);
#pragma unroll
    for (int ni = 0; ni < 4; ++ni)
      b[ni] = *(const short8*)(Bs + (wn * 64 + ni * 16 + l15) * 32 + quad * 8);
#pragma unroll
    for (int mi = 0; mi < 4; ++mi)
#pragma unroll
      for (int ni = 0; ni < 4; ++ni)
        acc[mi][ni] = __builtin_amdgcn_mfma_f32_16x16x32_bf16(a[mi], b[ni], acc[mi][ni], 0, 0, 0);
  }
#pragma unroll
  for (int mi = 0; mi < 4; ++mi) {
#pragma unroll
    for (int ni = 0; ni < 4; ++ni) {
      int n = nBase + wn * 64 + ni * 16 + l15;
      int h = n >> 9, d = n & 511;
#pragma unroll
      for (int r = 0; r < 4; ++r) {
        int m = mBase + wm * 64 + mi * 16 + quad * 4 + r;
        int b = m >> 10, s = m & 1023;
        long idx;
        if (z == 2) idx = ((long)(b * 8 + h) * 512 + d) * 1024 + s;   // V: (B,H,DK,S)
        else        idx = ((long)(b * 8 + h) * 1024 + s) * 512 + d;   // (B,H,S,DK)
        out[idx] = f2bf(acc[mi][ni][r]);
      }
    }
  }
}

// ---------------------------------------------------------------------------
// K2: flash attention (R13 lockstep structure; PV V-frags hoisted to regs).
//  - Ks XOR-swizzled: chunk j of key-row r lives at r*64 + (j ^ (r&7)).
//  - Vs XOR-swizzled: chunk j of d-row lives at d*4 + (j ^ (d&3)).
//  - Ps rows padded to 40 shorts.
//  - B0 sync; K DMAs; V DMAs; B1 = vmcnt(8)+barrier (V hides under QK^T);
//    B2 full drain -> lockstep / cross-block L2 sharing intact.
//  - NEW: vf[8] read from Vs ONCE per iter (after B2), reused across 4 g
//    -> PV LDS reads 128->32 KB/block-iter.
// ---------------------------------------------------------------------------
__global__ __launch_bounds__(256, 2) void flash_attn(
    const short* __restrict__ Qh, const short* __restrict__ Kh,
    const short* __restrict__ Vt, short* __restrict__ ctx)
{
  __shared__ __align__(16) short Ks[32 * 512];    // 32 KB, swizzled
  __shared__ __align__(16) short Vs[512 * 32];    // 32 KB, swizzled
  __shared__ __align__(16) short Ps[4 * 16 * 40]; // 5 KB, padded rows
  __shared__ float lred[64];
  const int tid = threadIdx.x;
  const int wave = tid >> 6, lane = tid & 63;
  const int quad = lane >> 4, l15 = lane & 15;
  const int lin = blockIdx.x;
  const int qt = (lin >> 3) & 15;
  const int bh = ((lin >> 7) << 3) | (lin & 7);
  const float C = 0.0637587234f;  // log2(e)/sqrt(512)

  // Q fragments for this wave's q-group (A-operand: A[m=l15][k=quad*8+j])
  const short* qbase = Qh + ((long)bh * 1024 + qt * 64 + wave * 16 + l15) * 512 + quad * 8;
  short8 qf[16];
#pragma unroll
  for (int c = 0; c < 16; ++c) qf[c] = *(const short8*)(qbase + c * 32);

  f32x4 acc[4][8] = {};               // O: [q-group][d-tile of this wave's slice]
  float l[4] = {0.f, 0.f, 0.f, 0.f};  // lane-local partial denominators

  for (int kt = 0; kt < 32; ++kt) {
    __syncthreads();  // B0: prior iter's Ks/Vs/Ps reads complete before overwrite
#pragma unroll
    for (int i = 0; i < 8; ++i) {     // K tile: source chunk permuted per row
      int c = i * 256 + tid;
      int r = c >> 6, j = (c & 63) ^ (r & 7);
      g2lds16(Kh + ((long)bh * 1024 + kt * 32 + r) * 512 + j * 8, (char*)Ks + c * 16);
    }
    __builtin_amdgcn_sched_barrier(0);  // pin issue order: K DMAs before V DMAs
#pragma unroll
    for (int i = 0; i < 8; ++i) {     // V tile: source chunk permuted per row
      int c = i * 256 + tid;
      int d = c >> 2, j = (c & 3) ^ (d & 3);
      g2lds16(Vt + ((long)bh * 512 + d) * 1024 + kt * 32 + j * 8, (char*)Vs + c * 16);
    }
    __builtin_amdgcn_sched_barrier(0);
    // B1: wait K's 8 DMAs only (V's 8 remain in flight, hidden under QK^T)
    asm volatile("s_waitcnt vmcnt(8)" ::: "memory");
    __builtin_amdgcn_s_barrier();
    __builtin_amdgcn_sched_barrier(0);

    // S = Q K^T : own q-group x 32 keys
    f32x4 sacc[2] = {};
#pragma unroll
    for (int nt = 0; nt < 2; ++nt)
#pragma unroll
      for (int c = 0; c < 16; ++c) {
        int row = nt * 16 + l15;
        int j = (c * 4 + quad) ^ (row & 7);
        short8 kf = *(const short8*)(Ks + row * 512 + j * 8);
        sacc[nt] = __builtin_amdgcn_mfma_f32_16x16x32_bf16(qf[c], kf, sacc[nt], 0, 0, 0);
      }
    // p = exp2(s*C); lane-local partial sums; P into padded LDS
#pragma unroll
    for (int r = 0; r < 4; ++r) {
      float p0 = exp2f(sacc[0][r] * C);
      float p1 = exp2f(sacc[1][r] * C);
      Ps[wave * 640 + (quad * 4 + r) * 40 + l15]      = f2bf(p0);
      Ps[wave * 640 + (quad * 4 + r) * 40 + 16 + l15] = f2bf(p1);
      l[r] += p0 + p1;
    }
    __syncthreads();  // B2: full drain (vmcnt->0: Vs landed; lgkm: Ps visible)

    // V fragments for this wave's 128-d slice: read ONCE, reuse across 4 g
    short8 vf[8];
#pragma unroll
    for (int t = 0; t < 8; ++t) {
      int row = wave * 128 + t * 16 + l15;
      int j = quad ^ (row & 3);
      vf[t] = *(const short8*)(Vs + row * 32 + j * 8);
    }
    // O += P V : all 4 q-groups x this wave's 128-d slice
#pragma unroll
    for (int g = 0; g < 4; ++g) {
      short8 pf = *(const short8*)(Ps + g * 640 + l15 * 40 + quad * 8);
#pragma unroll
      for (int t = 0; t < 8; ++t)
        acc[g][t] = __builtin_amdgcn_mfma_f32_16x16x32_bf16(pf, vf[t], acc[g][t], 0, 0, 0);
    }
  }
  // deferred denominator reduction (within each quad's 16 lanes)
#pragma unroll
  for (int r = 0; r < 4; ++r) {
    float t = l[r];
    t += __shfl_xor(t, 1);
    t += __shfl_xor(t, 2);
    t += __shfl_xor(t, 4);
    t += __shfl_xor(t, 8);
    l[r] = t;
  }
  if (l15 == 0) {
#pragma unroll
    for (int r = 0; r < 4; ++r) lred[wave * 16 + quad * 4 + r] = l[r];
  }
  __syncthreads();
  // epilogue: /l, store ctx (B,S,H*DK), this wave's d-slice
  const int b = bh >> 3, h = bh & 7;
#pragma unroll
  for (int g = 0; g < 4; ++g) {
#pragma unroll
    for (int r = 0; r < 4; ++r) {
      float inv = 1.0f / lred[g * 16 + quad * 4 + r];
      int qrow = qt * 64 + g * 16 + quad * 4 + r;
      long base = ((long)(b * 1024 + qrow)) * 4096 + h * 512 + wave * 128;
#pragma unroll
      for (int t = 0; t < 8; ++t)
        ctx[base + t * 16 + l15] = f2bf(acc[g][t][r] * inv);
    }
  }
}

// ---------------------------------------------------------------------------
// K3: fc + residual, both operands DMA-staged. M=8192, N=512, K=4096.
// R14: 128x64 tiles -> grid (64,8) = 512 blocks (2/CU, latency overlap).
// Per wave 64x32: acc[4][2]. B tile 64x32 = one DMA instr.
// ---------------------------------------------------------------------------
__global__ void fc_gemm(
    const short* __restrict__ A, const short* __restrict__ Wb,
    const float* __restrict__ resid, float* __restrict__ Y)
{
  __shared__ __align__(16) short As[128 * 32];
  __shared__ __align__(16) short Bs[64 * 32];
  const int tid = threadIdx.x;
  const int wave = tid >> 6, lane = tid & 63;
  const int quad = lane >> 4, l15 = lane & 15;
  const int mBase = blockIdx.x * 128, nBase = blockIdx.y * 64;
  const int wm = wave >> 1, wn = wave & 1;
  const int c0 = tid, c1 = tid + 256;
  const int r0 = c0 >> 2, o0 = (c0 & 3) * 8;
  const int r1 = c1 >> 2, o1 = (c1 & 3) * 8;
  f32x4 acc[4][2] = {};

  for (int k0 = 0; k0 < 4096; k0 += 32) {
    __syncthreads();
    g2lds16(A + (long)(mBase + r0) * 4096 + k0 + o0, (char*)As + c0 * 16);
    g2lds16(A + (long)(mBase + r1) * 4096 + k0 + o1, (char*)As + c1 * 16);
    g2lds16(Wb + (long)(nBase + r0) * 4096 + k0 + o0, (char*)Bs + c0 * 16);
    __syncthreads();  // drains vmcnt: tiles visible
    short8 a[4], b[2];
#pragma unroll
    for (int mi = 0; mi < 4; ++mi)
      a[mi] = *(const short8*)(As + (wm * 64 + mi * 16 + l15) * 32 + quad * 8);
#pragma unroll
    for (int ni = 0; ni < 2; ++ni)
      b[ni] = *(const short8*)(Bs + (wn * 32 + ni * 16 + l15) * 32 + quad * 8);
#pragma unroll
    for (int mi = 0; mi < 4; ++mi)
#pragma unroll
      for (int ni = 0; ni < 2; ++ni)
        acc[mi][ni] = __builtin_amdgcn_mfma_f32_16x16x32_bf16(a[mi], b[ni], acc[mi][ni], 0, 0, 0);
  }
#pragma unroll
  for (int mi = 0; mi < 4; ++mi)
#pragma unroll
    for (int ni = 0; ni < 2; ++ni) {
      int n = nBase + wn * 32 + ni * 16 + l15;
#pragma unroll
      for (int r = 0; r < 4; ++r) {
        int m = mBase + wm * 64 + mi * 16 + quad * 4 + r;
        long idx = (long)m * 512 + n;
        Y[idx] = acc[mi][ni][r] + resid[idx];
      }
    }
}

// ---------------------------------------------------------------------------
// K4: LayerNorm (unchanged).
// ---------------------------------------------------------------------------
__global__ void layernorm(
    const float* __restrict__ Y, const float* __restrict__ gamma,
    const float* __restrict__ beta, float* __restrict__ out)
{
  const int tid = threadIdx.x;
  const int wave = tid >> 6, lane = tid & 63;
  const long row = (long)blockIdx.x * 4 + wave;
  f32x4 xa = *(const f32x4*)(Y + row * 512 + lane * 8);
  f32x4 xb = *(const f32x4*)(Y + row * 512 + lane * 8 + 4);
  float x[8];
  float s = 0.f, s2 = 0.f;
#pragma unroll
  for (int i = 0; i < 4; ++i) { x[i] = xa[i]; x[i + 4] = xb[i]; }
#pragma unroll
  for (int i = 0; i < 8; ++i) { s += x[i]; s2 += x[i] * x[i]; }
#pragma unroll
  for (int m = 1; m < 64; m <<= 1) { s += __shfl_xor(s, m); s2 += __shfl_xor(s2, m); }
  float mu = s * (1.0f / 512.0f);
  float var = s2 * (1.0f / 512.0f) - mu * mu;
  float rs = rsqrtf(var + 1e-6f);
  f32x4 oa, ob;
#pragma unroll
  for (int i = 0; i < 4; ++i) {
    oa[i] = (x[i] - mu) * rs * gamma[lane * 8 + i] + beta[lane * 8 + i];
    ob[i] = (x[i + 4] - mu) * rs * gamma[lane * 8 + 4 + i] + beta[lane * 8 + 4 + i];
  }
  *(f32x4*)(out + row * 512 + lane * 8) = oa;
  *(f32x4*)(out + row * 512 + lane * 8 + 4) = ob;
}

extern "C" void kernel_launch(void* const* d_in, const int* in_sizes, int n_in,
                              void* d_out, int out_size, void* d_ws, size_t ws_size,
                              hipStream_t stream) {
  const float* q     = (const float*)d_in[0];
  const float* k     = (const float*)d_in[1];
  const float* v     = (const float*)d_in[2];
  const float* wq    = (const float*)d_in[3];
  const float* wk    = (const float*)d_in[4];
  const float* wv    = (const float*)d_in[5];
  const float* wfc   = (const float*)d_in[6];
  const float* gamma = (const float*)d_in[7];
  const float* beta  = (const float*)d_in[8];
  float* out = (float*)d_out;
  char* ws = (char*)d_ws;
  short* Qh  = (short*)(ws);                    // [0,64M)   bf16, dead after attn
  short* Kh  = (short*)(ws + 67108864);         // [64,128M)
  short* Vt  = (short*)(ws + 134217728);        // [128,192M)
  short* ctx = (short*)(ws + 201326592);        // [192,256M) attn out (bf16)
  // cvt6 outputs live in the ctx region BEFORE attn overwrites it:
  short* xb  = (short*)(ws + 201326592);        // q/k/v bf16: 3 x 8 MB
  short* wb  = xb + 3 * 4194304;                // wq/wk/wv bf16: 3 x 4 MB
  // wfc bf16 lives in the dead-Qh region AFTER attn (Y uses [0,16M) fp32):
  short* wfcb = (short*)(ws + 16777216);        // [16,20M)
  float* Y   = (float*)(ws);                    // fp32 [0,16M), aliases dead Qh

  cvt6<<<dim3(1024, 1, 6), 256, 0, stream>>>(q, k, v, wq, wk, wv, xb, wb);
  qkv_proj<<<dim3(64, 32, 3), 256, 0, stream>>>(xb, wb, Qh, Kh, Vt);
  flash_attn<<<dim3(1024), 256, 0, stream>>>(Qh, Kh, Vt, ctx);
  cvt1<<<dim3(1024), 256, 0, stream>>>(wfc, wfcb, 262144);
  fc_gemm<<<dim3(64, 8), 256, 0, stream>>>(ctx, wfcb, q, Y);
  layernorm<<<2048, 256, 0, stream>>>(Y, gamma, beta, out);
}